// Round 3
// baseline (89958.044 us; speedup 1.0000x reference)
//
#include <hip/hip_runtime.h>
#include <stdint.h>

#define NB 64
#define NT 2048
#define ND 1024
#define NU 1024

typedef __attribute__((ext_vector_type(8))) short bf16x8;
typedef __attribute__((ext_vector_type(4))) float f32x4;

__device__ __forceinline__ unsigned short f2bf(float f) {
  union { float f; unsigned u; } v; v.f = f;
  return (unsigned short)((v.u + 0x7FFFu + ((v.u >> 16) & 1u)) >> 16);
}

// ---------------- init: zero legacy bar + tagged h double-buffer (tag=0) ----------------
__global__ void init_ws(unsigned* __restrict__ ws) {
  const int n = 1024 + 2 * NB * NU;  // 1024 legacy + 131072 tagged-h words
  for (int i = blockIdx.x * blockDim.x + threadIdx.x; i < n; i += gridDim.x * blockDim.x)
    ws[i] = 0u;
}

// ---------------- xp = inputs @ W_x + b  (bf16 MFMA, 128x128 tile) ----------------
__launch_bounds__(256, 3)
__global__ void gemm_xp(const float* __restrict__ inp, const float* __restrict__ Wx,
                        const float* __restrict__ bias, float* __restrict__ xp,
                        int t0, int Tc) {
  __shared__ unsigned short As[128][56];
  __shared__ unsigned short Bs[128][56];

  const int tid = threadIdx.x;
  const int u0 = blockIdx.x * 128;
  const int m_base = blockIdx.y * 128;
  const int b = m_base / Tc;
  const int tc0 = m_base % Tc;
  const size_t arow0 = ((size_t)b * NT + t0 + tc0) * (size_t)ND;

  const int w = tid >> 6, lane = tid & 63;
  const int wr = w >> 1, wc = w & 1;
  const int l15 = lane & 15, lk = lane >> 4;
  const int srow = tid & 127;
  const int shalf = tid >> 7;

  f32x4 acc[4][4];
  #pragma unroll
  for (int i = 0; i < 4; ++i)
    #pragma unroll
    for (int j = 0; j < 4; ++j)
      acc[i][j] = (f32x4){0.f, 0.f, 0.f, 0.f};

  for (int k0 = 0; k0 < ND; k0 += 32) {
    __syncthreads();
    {
      const float* src = inp + arow0 + (size_t)srow * ND + k0 + shalf * 16;
      unsigned short tmp[16];
      #pragma unroll
      for (int i = 0; i < 16; i += 4) {
        float4 v = *(const float4*)(src + i);
        tmp[i + 0] = f2bf(v.x); tmp[i + 1] = f2bf(v.y);
        tmp[i + 2] = f2bf(v.z); tmp[i + 3] = f2bf(v.w);
      }
      #pragma unroll
      for (int h = 0; h < 2; ++h) {
        bf16x8 pv;
        #pragma unroll
        for (int j = 0; j < 8; ++j) pv[j] = (short)tmp[h * 8 + j];
        *(bf16x8*)&As[srow][shalf * 16 + h * 8] = pv;
      }
    }
    {
      const float* src = Wx + (size_t)(k0 + shalf * 16) * NU + u0 + srow;
      unsigned short tmp[16];
      #pragma unroll
      for (int i = 0; i < 16; ++i) tmp[i] = f2bf(src[(size_t)i * NU]);
      #pragma unroll
      for (int h = 0; h < 2; ++h) {
        bf16x8 pv;
        #pragma unroll
        for (int j = 0; j < 8; ++j) pv[j] = (short)tmp[h * 8 + j];
        *(bf16x8*)&Bs[srow][shalf * 16 + h * 8] = pv;
      }
    }
    __syncthreads();

    bf16x8 af[4], bfr[4];
    #pragma unroll
    for (int mf = 0; mf < 4; ++mf)
      af[mf] = *(const bf16x8*)&As[wr * 64 + mf * 16 + l15][lk * 8];
    #pragma unroll
    for (int nf = 0; nf < 4; ++nf)
      bfr[nf] = *(const bf16x8*)&Bs[wc * 64 + nf * 16 + l15][lk * 8];
    #pragma unroll
    for (int mf = 0; mf < 4; ++mf)
      #pragma unroll
      for (int nf = 0; nf < 4; ++nf)
        acc[mf][nf] = __builtin_amdgcn_mfma_f32_16x16x32_bf16(af[mf], bfr[nf], acc[mf][nf], 0, 0, 0);
  }

  #pragma unroll
  for (int nf = 0; nf < 4; ++nf) {
    const int col = u0 + wc * 64 + nf * 16 + l15;
    const float bv = bias[col];
    #pragma unroll
    for (int mf = 0; mf < 4; ++mf) {
      const int rbase = m_base + wr * 64 + mf * 16 + lk * 4;
      #pragma unroll
      for (int r = 0; r < 4; ++r)
        xp[(size_t)(rbase + r) * NU + col] = acc[mf][nf][r] + bv;
    }
  }
}

// ---------------- persistent recurrent scan, barrier-free (tag-in-data) ----------------
// 32 WGs x 512 threads; WG owns 32 output columns, W_h slice in VGPRs.
// h element = u32 word: (step_tag << 16) | bf16(h). Consumers spin-load
// fragments until all tags match the step -> no barrier, no fences.
__launch_bounds__(512, 1)
__global__ void scan_kernel(const float* __restrict__ Wh, const float* __restrict__ xp,
                            unsigned* __restrict__ hw, float* __restrict__ out,
                            int t0, int Tc) {
  __shared__ float Red[4][2][32][36];  // [k4][m2][col][row(+pad)] f32 partials

  const int tid = threadIdx.x;
  const int wid = blockIdx.x;   // 0..31
  const int col0 = wid * 32;
  const int lane = tid & 63;
  const int w = tid >> 6;       // 0..7
  const int k4 = w & 3;         // K-group: k in [k4*256, +256)
  const int m2 = w >> 2;        // M-half: rows [m2*32, +32)
  const int l15 = lane & 15;
  const int lk = lane >> 4;

  // ---- persistent W_h B-fragments in VGPRs ----
  bf16x8 Bf[2][8];
  #pragma unroll
  for (int nf = 0; nf < 2; ++nf)
    for (int kq = 0; kq < 8; ++kq) {
      const int kk = k4 * 8 + kq;
      const int col = col0 + nf * 16 + l15;
      bf16x8 v;
      #pragma unroll
      for (int j = 0; j < 8; ++j) {
        const int k = kk * 32 + lk * 8 + j;
        v[j] = (short)f2bf(Wh[(size_t)k * NU + col]);
      }
      Bf[nf][kq] = v;
    }

  // reduce/store mapping: thread -> (1 col, 4 rows); lanes span 32 consecutive cols
  const int rcol = tid & 31;
  const int rgrp = tid >> 5;        // 0..15
  const int rrow = rgrp * 4;        // 0..60
  const int rm = rgrp >> 3;         // m-half
  const int rl = (rgrp & 7) * 4;    // row-in-half base

  for (int tc = 0; tc < Tc; ++tc) {
    const int t = t0 + tc;
    const unsigned expc = (unsigned)t & 0xffffu;
    const unsigned tagw = ((unsigned)(t + 1) & 0xffffu) << 16;
    const unsigned* hc = hw + (size_t)(t & 1) * (NB * NU);
    unsigned* hn = hw + (size_t)((t + 1) & 1) * (NB * NU);

    // xp prefetch (independent of h)
    float xpv[4];
    #pragma unroll
    for (int r = 0; r < 4; ++r)
      xpv[r] = xp[((size_t)(rrow + r) * Tc + tc) * NU + col0 + rcol];

    // ---- tagged A-load with retry: spin until every word carries tag t ----
    unsigned wv[16][8];  // [kq*2+mf][j]
    const unsigned* pb = hc + (size_t)(m2 * 32 + l15) * NU + k4 * 256 + lk * 8;
    for (;;) {
      #pragma unroll
      for (int kq = 0; kq < 8; ++kq)
        #pragma unroll
        for (int mf = 0; mf < 2; ++mf) {
          const unsigned* p = pb + (size_t)mf * 16 * NU + kq * 32;
          #pragma unroll
          for (int j = 0; j < 8; ++j)
            wv[kq * 2 + mf][j] =
                __hip_atomic_load(p + j, __ATOMIC_RELAXED, __HIP_MEMORY_SCOPE_AGENT);
        }
      unsigned d = 0;
      #pragma unroll
      for (int i = 0; i < 16; ++i)
        #pragma unroll
        for (int j = 0; j < 8; ++j)
          d |= (wv[i][j] >> 16) ^ expc;
      if (__all(d == 0)) break;
    }

    // ---- MFMA: extract bf16 low halves, B from VGPRs ----
    f32x4 acc[2][2];
    #pragma unroll
    for (int mf = 0; mf < 2; ++mf)
      #pragma unroll
      for (int nf = 0; nf < 2; ++nf)
        acc[mf][nf] = (f32x4){0.f, 0.f, 0.f, 0.f};

    #pragma unroll
    for (int kq = 0; kq < 8; ++kq)
      #pragma unroll
      for (int mf = 0; mf < 2; ++mf) {
        union { unsigned u[4]; bf16x8 v; } a;
        #pragma unroll
        for (int jj = 0; jj < 4; ++jj)
          a.u[jj] = (wv[kq * 2 + mf][2 * jj] & 0xffffu) | (wv[kq * 2 + mf][2 * jj + 1] << 16);
        acc[mf][0] = __builtin_amdgcn_mfma_f32_16x16x32_bf16(a.v, Bf[0][kq], acc[mf][0], 0, 0, 0);
        acc[mf][1] = __builtin_amdgcn_mfma_f32_16x16x32_bf16(a.v, Bf[1][kq], acc[mf][1], 0, 0, 0);
      }

    __syncthreads();  // prev-step Red reads complete before overwrite
    #pragma unroll
    for (int mf = 0; mf < 2; ++mf)
      #pragma unroll
      for (int nf = 0; nf < 2; ++nf)
        *(f32x4*)&Red[k4][m2][nf * 16 + l15][mf * 16 + lk * 4] = acc[mf][nf];
    __syncthreads();

    // ---- reduce + xp + tanh -> tagged coalesced stores (no barrier after) ----
    {
      f32x4 s = *(const f32x4*)&Red[0][rm][rcol][rl];
      s += *(const f32x4*)&Red[1][rm][rcol][rl];
      s += *(const f32x4*)&Red[2][rm][rcol][rl];
      s += *(const f32x4*)&Red[3][rm][rcol][rl];
      #pragma unroll
      for (int r = 0; r < 4; ++r) {
        const float z = s[r] + xpv[r];
        const float e = __expf(2.0f * z);
        const float hv = 1.0f - 2.0f / (e + 1.0f);   // tanh(z), saturates safely
        if (t == NT - 1) out[(size_t)(rrow + r) * NU + col0 + rcol] = hv;
        const unsigned word = tagw | (unsigned)f2bf(hv);
        __hip_atomic_store(hn + (size_t)(rrow + r) * NU + col0 + rcol, word,
                           __ATOMIC_RELAXED, __HIP_MEMORY_SCOPE_AGENT);
      }
    }
  }
}

extern "C" void kernel_launch(void* const* d_in, const int* in_sizes, int n_in,
                              void* d_out, int out_size, void* d_ws, size_t ws_size,
                              hipStream_t stream) {
  (void)in_sizes; (void)n_in; (void)out_size;
  const float* inp  = (const float*)d_in[0];
  const float* Wx   = (const float*)d_in[1];
  const float* Wh   = (const float*)d_in[2];
  const float* bias = (const float*)d_in[3];
  float* out = (float*)d_out;

  unsigned* hw = (unsigned*)((char*)d_ws + 4096);                  // 512 KB tagged h x2
  const size_t xp_off = 4096 + (size_t)2 * NB * NU * sizeof(unsigned);
  float* xp = (float*)((char*)d_ws + xp_off);
  const size_t avail = (ws_size > xp_off) ? ws_size - xp_off : 0;

  int Tc = 128;
  for (int cand = NT; cand >= 128; cand >>= 1)
    if ((size_t)NB * (size_t)cand * NU * sizeof(float) <= avail) { Tc = cand; break; }

  init_ws<<<dim3(128), dim3(256), 0, stream>>>((unsigned*)d_ws);

  for (int t0 = 0; t0 < NT; t0 += Tc) {
    gemm_xp<<<dim3(8, (NB * Tc) / 128), dim3(256), 0, stream>>>(inp, Wx, bias, xp, t0, Tc);
    scan_kernel<<<dim3(32), dim3(512), 0, stream>>>(Wh, xp, hw, out, t0, Tc);
  }
}

// Round 4
// 20994.664 us; speedup vs baseline: 4.2848x; 4.2848x over previous
//
#include <hip/hip_runtime.h>
#include <stdint.h>

#define NB 64
#define NT 2048
#define ND 1024
#define NU 1024
#define FLAG_STRIDE 16  // flags 64B apart -> parallel, no shared-line convoy

typedef __attribute__((ext_vector_type(8))) short bf16x8;
typedef __attribute__((ext_vector_type(4))) float f32x4;
typedef unsigned long long u64;

__device__ __forceinline__ unsigned short f2bf(float f) {
  union { float f; unsigned u; } v; v.f = f;
  return (unsigned short)((v.u + 0x7FFFu + ((v.u >> 16) & 1u)) >> 16);
}

// ---------------- init: zero flag area + h double-buffer ----------------
__global__ void init_ws(unsigned* __restrict__ ws) {
  const int n = 1024 + (2 * NB * NU) / 2;  // 1024 flag/ctrl words + 65536 words (256KB bf16 h x2)
  for (int i = blockIdx.x * blockDim.x + threadIdx.x; i < n; i += gridDim.x * blockDim.x)
    ws[i] = 0u;
}

// ---------------- xp = inputs @ W_x + b  (bf16 MFMA, 128x128 tile) ----------------
__launch_bounds__(256, 3)
__global__ void gemm_xp(const float* __restrict__ inp, const float* __restrict__ Wx,
                        const float* __restrict__ bias, float* __restrict__ xp,
                        int t0, int Tc) {
  __shared__ unsigned short As[128][56];
  __shared__ unsigned short Bs[128][56];

  const int tid = threadIdx.x;
  const int u0 = blockIdx.x * 128;
  const int m_base = blockIdx.y * 128;
  const int b = m_base / Tc;
  const int tc0 = m_base % Tc;
  const size_t arow0 = ((size_t)b * NT + t0 + tc0) * (size_t)ND;

  const int w = tid >> 6, lane = tid & 63;
  const int wr = w >> 1, wc = w & 1;
  const int l15 = lane & 15, lk = lane >> 4;
  const int srow = tid & 127;
  const int shalf = tid >> 7;

  f32x4 acc[4][4];
  #pragma unroll
  for (int i = 0; i < 4; ++i)
    #pragma unroll
    for (int j = 0; j < 4; ++j)
      acc[i][j] = (f32x4){0.f, 0.f, 0.f, 0.f};

  for (int k0 = 0; k0 < ND; k0 += 32) {
    __syncthreads();
    {
      const float* src = inp + arow0 + (size_t)srow * ND + k0 + shalf * 16;
      unsigned short tmp[16];
      #pragma unroll
      for (int i = 0; i < 16; i += 4) {
        float4 v = *(const float4*)(src + i);
        tmp[i + 0] = f2bf(v.x); tmp[i + 1] = f2bf(v.y);
        tmp[i + 2] = f2bf(v.z); tmp[i + 3] = f2bf(v.w);
      }
      #pragma unroll
      for (int h = 0; h < 2; ++h) {
        bf16x8 pv;
        #pragma unroll
        for (int j = 0; j < 8; ++j) pv[j] = (short)tmp[h * 8 + j];
        *(bf16x8*)&As[srow][shalf * 16 + h * 8] = pv;
      }
    }
    {
      const float* src = Wx + (size_t)(k0 + shalf * 16) * NU + u0 + srow;
      unsigned short tmp[16];
      #pragma unroll
      for (int i = 0; i < 16; ++i) tmp[i] = f2bf(src[(size_t)i * NU]);
      #pragma unroll
      for (int h = 0; h < 2; ++h) {
        bf16x8 pv;
        #pragma unroll
        for (int j = 0; j < 8; ++j) pv[j] = (short)tmp[h * 8 + j];
        *(bf16x8*)&Bs[srow][shalf * 16 + h * 8] = pv;
      }
    }
    __syncthreads();

    bf16x8 af[4], bfr[4];
    #pragma unroll
    for (int mf = 0; mf < 4; ++mf)
      af[mf] = *(const bf16x8*)&As[wr * 64 + mf * 16 + l15][lk * 8];
    #pragma unroll
    for (int nf = 0; nf < 4; ++nf)
      bfr[nf] = *(const bf16x8*)&Bs[wc * 64 + nf * 16 + l15][lk * 8];
    #pragma unroll
    for (int mf = 0; mf < 4; ++mf)
      #pragma unroll
      for (int nf = 0; nf < 4; ++nf)
        acc[mf][nf] = __builtin_amdgcn_mfma_f32_16x16x32_bf16(af[mf], bfr[nf], acc[mf][nf], 0, 0, 0);
  }

  #pragma unroll
  for (int nf = 0; nf < 4; ++nf) {
    const int col = u0 + wc * 64 + nf * 16 + l15;
    const float bv = bias[col];
    #pragma unroll
    for (int mf = 0; mf < 4; ++mf) {
      const int rbase = m_base + wr * 64 + mf * 16 + lk * 4;
      #pragma unroll
      for (int r = 0; r < 4; ++r)
        xp[(size_t)(rbase + r) * NU + col] = acc[mf][nf][r] + bv;
    }
  }
}

// ---------------- persistent recurrent scan, flag-array sync ----------------
// 32 WGs x 512 threads; WG owns 32 output columns, W_h slice in VGPRs.
// Per step: wave (k4,m2) polls the 8 flags of the WGs producing its K-range,
// loads h via sc1 u64 atomics, MFMA, LDS K-reduce, tanh, coalesced u32 h
// stores, release flag store. No counters, no RMW convoy.
__launch_bounds__(512, 1)
__global__ void scan_kernel(const float* __restrict__ Wh, const float* __restrict__ xp,
                            unsigned short* __restrict__ hbuf, float* __restrict__ out,
                            unsigned* __restrict__ flags, int t0, int Tc) {
  __shared__ float Red[4][2][32][36];  // [k4][m2][col][row(+pad)] f32 partials

  const int tid = threadIdx.x;
  const int wid = blockIdx.x;   // 0..31
  const int col0 = wid * 32;
  const int lane = tid & 63;
  const int w = tid >> 6;       // 0..7
  const int k4 = w & 3;         // K-group: k in [k4*256, +256)
  const int m2 = w >> 2;        // M-half: rows [m2*32, +32)
  const int l15 = lane & 15;
  const int lk = lane >> 4;

  // ---- persistent W_h B-fragments in VGPRs ----
  bf16x8 Bf[2][8];
  #pragma unroll
  for (int nf = 0; nf < 2; ++nf)
    for (int kq = 0; kq < 8; ++kq) {
      const int kk = k4 * 8 + kq;
      const int col = col0 + nf * 16 + l15;
      bf16x8 v;
      #pragma unroll
      for (int j = 0; j < 8; ++j) {
        const int k = kk * 32 + lk * 8 + j;
        v[j] = (short)f2bf(Wh[(size_t)k * NU + col]);
      }
      Bf[nf][kq] = v;
    }

  // reduce/store mapping: thread -> (1 col, 4 rows)
  const int rcol = tid & 31;
  const int rgrp = tid >> 5;        // 0..15
  const int rrow = rgrp * 4;        // 0..60
  const int rm = rgrp >> 3;         // m-half
  const int rl = (rgrp & 7) * 4;    // row-in-half base

  // this wave's flag-poll target set: producers of cols [k4*256, +256) = WGs k4*8..+8
  const unsigned* fpoll = flags + (size_t)(k4 * 8 + (lane & 7)) * FLAG_STRIDE;
  unsigned* fown = flags + (size_t)wid * FLAG_STRIDE;

  for (int tc = 0; tc < Tc; ++tc) {
    const int t = t0 + tc;
    const unsigned short* hc = hbuf + (size_t)(t & 1) * (NB * NU);
    unsigned short* hn = hbuf + (size_t)((t + 1) & 1) * (NB * NU);

    // xp prefetch (independent of h) -- issue before the poll to hide latency
    float xpv[4];
    #pragma unroll
    for (int r = 0; r < 4; ++r)
      xpv[r] = xp[((size_t)(rrow + r) * Tc + tc) * NU + col0 + rcol];

    // ---- poll the 8 producer flags for this wave's K-range ----
    if (t != 0) {
      const unsigned tgt = (unsigned)t;
      for (;;) {
        unsigned fv = tgt;
        if (lane < 8)
          fv = __hip_atomic_load(fpoll, __ATOMIC_RELAXED, __HIP_MEMORY_SCOPE_AGENT);
        if (__all((int)(fv >= tgt))) break;
      }
      asm volatile("" ::: "memory");  // keep h loads below the poll
    }

    // ---- MFMA: A (h_t) via sc1 u64 loads, B from VGPRs ----
    f32x4 acc[2][2];
    #pragma unroll
    for (int mf = 0; mf < 2; ++mf)
      #pragma unroll
      for (int nf = 0; nf < 2; ++nf)
        acc[mf][nf] = (f32x4){0.f, 0.f, 0.f, 0.f};

    #pragma unroll
    for (int kq = 0; kq < 8; ++kq) {
      const int kk = k4 * 8 + kq;
      #pragma unroll
      for (int mf = 0; mf < 2; ++mf) {
        const int row = m2 * 32 + mf * 16 + l15;
        const u64* p = (const u64*)(hc + (size_t)row * NU + kk * 32 + lk * 8);
        const u64 q0 = __hip_atomic_load(p,     __ATOMIC_RELAXED, __HIP_MEMORY_SCOPE_AGENT);
        const u64 q1 = __hip_atomic_load(p + 1, __ATOMIC_RELAXED, __HIP_MEMORY_SCOPE_AGENT);
        union { u64 q[2]; bf16x8 v; } u; u.q[0] = q0; u.q[1] = q1;
        acc[mf][0] = __builtin_amdgcn_mfma_f32_16x16x32_bf16(u.v, Bf[0][kq], acc[mf][0], 0, 0, 0);
        acc[mf][1] = __builtin_amdgcn_mfma_f32_16x16x32_bf16(u.v, Bf[1][kq], acc[mf][1], 0, 0, 0);
      }
    }

    // write K-partials (prev-step Red reads are already fenced by sync B below)
    #pragma unroll
    for (int mf = 0; mf < 2; ++mf)
      #pragma unroll
      for (int nf = 0; nf < 2; ++nf)
        *(f32x4*)&Red[k4][m2][nf * 16 + l15][mf * 16 + lk * 4] = acc[mf][nf];
    __syncthreads();  // sync A: partials visible

    // ---- reduce + xp + tanh -> packed u32 coalesced h stores ----
    {
      f32x4 s = *(const f32x4*)&Red[0][rm][rcol][rl];
      s += *(const f32x4*)&Red[1][rm][rcol][rl];
      s += *(const f32x4*)&Red[2][rm][rcol][rl];
      s += *(const f32x4*)&Red[3][rm][rcol][rl];
      #pragma unroll
      for (int r = 0; r < 4; ++r) {
        const float z = s[r] + xpv[r];
        const float e = __expf(2.0f * z);
        const float hv = 1.0f - 2.0f / (e + 1.0f);   // tanh(z), saturates safely
        if (t == NT - 1) out[(size_t)(rrow + r) * NU + col0 + rcol] = hv;
        const unsigned mybf = f2bf(hv);
        const unsigned nb = (unsigned)__shfl_xor((int)mybf, 1);
        if ((tid & 1) == 0) {
          const unsigned word = mybf | (nb << 16);
          __hip_atomic_store((unsigned*)(hn + (size_t)(rrow + r) * NU + col0 + rcol), word,
                             __ATOMIC_RELAXED, __HIP_MEMORY_SCOPE_AGENT);
        }
      }
    }
    __syncthreads();  // sync B: drains all waves' h stores (vmcnt 0) + guards Red reuse

    if (tid == 0)     // release: h_t+1 globally visible before flag says so
      __hip_atomic_store(fown, (unsigned)(t + 1), __ATOMIC_RELEASE, __HIP_MEMORY_SCOPE_AGENT);
  }
}

extern "C" void kernel_launch(void* const* d_in, const int* in_sizes, int n_in,
                              void* d_out, int out_size, void* d_ws, size_t ws_size,
                              hipStream_t stream) {
  (void)in_sizes; (void)n_in; (void)out_size;
  const float* inp  = (const float*)d_in[0];
  const float* Wx   = (const float*)d_in[1];
  const float* Wh   = (const float*)d_in[2];
  const float* bias = (const float*)d_in[3];
  float* out = (float*)d_out;

  unsigned* flags = (unsigned*)d_ws;                               // 4 KB flag area
  unsigned short* hbuf = (unsigned short*)((char*)d_ws + 4096);    // 256 KB h double-buffer
  const size_t xp_off = 4096 + (size_t)2 * NB * NU * sizeof(unsigned short);
  float* xp = (float*)((char*)d_ws + xp_off);
  const size_t avail = (ws_size > xp_off) ? ws_size - xp_off : 0;

  int Tc = 128;
  for (int cand = NT; cand >= 128; cand >>= 1)
    if ((size_t)NB * (size_t)cand * NU * sizeof(float) <= avail) { Tc = cand; break; }

  init_ws<<<dim3(128), dim3(256), 0, stream>>>((unsigned*)d_ws);

  for (int t0 = 0; t0 < NT; t0 += Tc) {
    gemm_xp<<<dim3(8, (NB * Tc) / 128), dim3(256), 0, stream>>>(inp, Wx, bias, xp, t0, Tc);
    scan_kernel<<<dim3(32), dim3(512), 0, stream>>>(Wh, xp, hbuf, out, flags, t0, Tc);
  }
}